// Round 5
// baseline (143.585 us; speedup 1.0000x reference)
//
#include <hip/hip_runtime.h>

// Problem constants
#define Gn 256
#define Nn 512
#define En 4096
#define Fn 64
#define Cn 16
#define ET (En + Nn)   // CSR slots including self-loops

typedef _Float16 halfv8 __attribute__((ext_vector_type(8)));
typedef _Float16 halfv4 __attribute__((ext_vector_type(4)));
typedef _Float16 halfv2 __attribute__((ext_vector_type(2)));
typedef float    f32x4  __attribute__((ext_vector_type(4)));

__device__ __forceinline__ float pk_norm(unsigned p) {
    return (float)__builtin_bit_cast(_Float16, (unsigned short)(p & 0xffffu));
}

// LDS-only barrier: waits DS ops, leaves global loads in flight. All
// cross-thread data in this kernel moves through LDS, so lgkmcnt(0) is
// sufficient; __syncthreads would drain vmcnt(0) and serialize the x stream
// against the edge pipeline. Correctness-verified in R9 AND R10.
__device__ __forceinline__ void bar_lds() {
    asm volatile("s_waitcnt lgkmcnt(0)" ::: "memory");
    __builtin_amdgcn_s_barrier();
    __builtin_amdgcn_sched_barrier(0);
}

// ---------------- K0: lw f32 -> f16 (one-time, consumed by K1 tail) ----------
__global__ __launch_bounds__(256) void cvt_lw(
    const float* __restrict__ lw,     // [16][32768] fp32
    _Float16* __restrict__ lwh)       // ws: [16][32768] f16
{
    const int i = blockIdx.x * 256 + threadIdx.x;   // 65536 threads x 8 floats
    float4 a = *((const float4*)lw + (size_t)i * 2);
    float4 b = *((const float4*)lw + (size_t)i * 2 + 1);
    halfv8 hv;
    hv[0]=(_Float16)a.x; hv[1]=(_Float16)a.y; hv[2]=(_Float16)a.z; hv[3]=(_Float16)a.w;
    hv[4]=(_Float16)b.x; hv[5]=(_Float16)b.y; hv[6]=(_Float16)b.z; hv[7]=(_Float16)b.w;
    *(halfv8*)(lwh + (size_t)i * 8) = hv;
}

// ---------------- K1: fully fused GCN per graph ----------------
// One block per graph (256 = #CUs), 1024 thr = 16 waves, ~158 KB LDS.
// R11 = R8's proven structure (43us kernel: all 1024 threads hold xv[8],
// ~45 live VGPRs, no spill) + exactly two verified grafts:
//  (1) bar_lds instead of __syncthreads: degree atomics wait only the edge
//      loads (vmcnt(10)), so the x stream overlaps atomics+scan+CSR;
//  (2) R10's tail: single ds_read_b128 slot-pair + direct lw loads,
//      no register arrays (R9/R10 spilled via pinned arrays - rule #20).
__global__ __launch_bounds__(1024, 4) void gcn_fused(
    const float* __restrict__ x,      // [G,N,F]
    const int*   __restrict__ ei,     // [G,2,E]
    const float* __restrict__ w,      // [F_OUT,F_IN] = [64,64]
    const float* __restrict__ wbias,  // [64]
    const _Float16* __restrict__ lwh, // ws: [16][32768] f16 (from K0)
    const float* __restrict__ lbias,  // [16]
    float* __restrict__ out)          // [G,16] log-softmax
{
    __shared__ unsigned short xs_h[Nn * Fn];  // 64 KB: f16 x; reused for f16 h
    __shared__ unsigned short xhs[Nn * Fn];   // 64 KB: f16 aggregated, swizzled
    __shared__ unsigned short wts[Fn * Fn];   // 8 KB: f16 w rows, swizzled
    __shared__ unsigned int   epk[ET + 8];    // 18.5 KB: (src<<16)|f16(norm)
    __shared__ float dinv[Nn];                // degree -> rsqrt; reused: logits
    __shared__ int   cnt[Nn];                 // excl -> incl prefix
    __shared__ int   wsum[8];

    const int g    = blockIdx.x;
    const int tid  = threadIdx.x;
    const int lane = tid & 63;
    const int wid  = tid >> 6;

    const float* xg = x + (size_t)g * Nn * Fn;
    const int*   es = ei + (size_t)g * 2 * En;   // sources
    const int*   ed = es + En;                    // targets

    // ---- issue ei FIRST, then x, w, lbias: the degree atomics' vmcnt wait
    // releases with x/w still streaming (bar_lds never drains them) ----
    const int e0s = es[tid], e1s = es[tid + 1024], e2s = es[tid + 2048], e3s = es[tid + 3072];
    const int e0t = ed[tid], e1t = ed[tid + 1024], e2t = ed[tid + 2048], e3t = ed[tid + 3072];
    float4 xv[8];
    #pragma unroll
    for (int it = 0; it < 8; ++it) xv[it] = *(const float4*)(xg + (tid + it * 1024) * 4);
    const float4 wv = *(const float4*)(w + (tid >> 4) * Fn + (tid & 15) * 4);
    const float lbv = (tid < Cn) ? lbias[tid] : 0.0f;

    if (tid < Nn) dinv[tid] = 1.0f;               // self-loop counts as 1
    bar_lds();                                 // sync0: dinv init visible

    // ---- degree atomics from register-held targets (waits ei only) ----
    atomicAdd(&dinv[e0t], 1.0f);
    atomicAdd(&dinv[e1t], 1.0f);
    atomicAdd(&dinv[e2t], 1.0f);
    atomicAdd(&dinv[e3t], 1.0f);
    bar_lds();                                 // sync1

    // ---- per-node slot count (incl self) + dinv; exclusive prefix scan ----
    int c = 0;
    if (tid < Nn) { float d = dinv[tid]; c = (int)d; dinv[tid] = rsqrtf(d); }
    int v_ = c;
    #pragma unroll
    for (int off = 1; off < 64; off <<= 1) {
        int u = __shfl_up(v_, off, 64);
        if (lane >= off) v_ += u;
    }
    if (wid < 8 && lane == 63) wsum[wid] = v_;
    bar_lds();                                 // sync2
    if (tid == 0) { int a = 0; for (int i = 0; i < 8; ++i) { int t = wsum[i]; wsum[i] = a; a += t; } }
    bar_lds();                                 // sync3
    if (tid < Nn) cnt[tid] = v_ - c + wsum[wid];
    bar_lds();                                 // sync4

    // ---- CSR fill (edges from regs + self-loops) with packed src|norm ----
    {
        #define FILL_EDGE(ss, tt) { \
            float nrm = dinv[ss] * dinv[tt]; \
            int slot = atomicAdd(&cnt[tt], 1); \
            unsigned short nb = __builtin_bit_cast(unsigned short, (_Float16)nrm); \
            epk[slot] = ((unsigned)(ss) << 16) | nb; }
        FILL_EDGE(e0s, e0t)
        FILL_EDGE(e1s, e1t)
        FILL_EDGE(e2s, e2t)
        FILL_EDGE(e3s, e3t)
        #undef FILL_EDGE
        if (tid < Nn) {
            float dv = dinv[tid];
            float nrm = dv * dv;
            int slot = atomicAdd(&cnt[tid], 1);
            unsigned short nb = __builtin_bit_cast(unsigned short, (_Float16)nrm);
            epk[slot] = ((unsigned)tid << 16) | nb;
        }
    }

    // ---- stage w (f16, swizzled) ----
    {
        int o = tid >> 4, f0 = (tid & 15) * 4;
        halfv4 hv; hv[0]=(_Float16)wv.x; hv[1]=(_Float16)wv.y;
                   hv[2]=(_Float16)wv.z; hv[3]=(_Float16)wv.w;
        int blk = f0 >> 3, hf = (f0 >> 2) & 1;    // 16B-block XOR swizzle by row
        *(halfv4*)((char*)wts + o * 128 + ((blk ^ (o & 7)) * 16) + hf * 8) = hv;
    }

    // ---- stage x (f16): x stream lands here, overlapped with scan+CSR ----
    #pragma unroll
    for (int it = 0; it < 8; ++it) {
        int idx = tid + it * 1024;                // float4 index (8192 total)
        float4 v = xv[it];
        halfv4 hv; hv[0]=(_Float16)v.x; hv[1]=(_Float16)v.y;
                   hv[2]=(_Float16)v.z; hv[3]=(_Float16)v.w;
        *(halfv4*)((char*)xs_h + idx * 8) = hv;   // natural [n][f] layout
    }
    bar_lds();                                 // sync5: epk/cnt/xs_h/wts ready

    // ---- gather: quarter-wave per target, all-LDS, 4-wide pipelined ----
    {
        const int qid = lane >> 4, fl = lane & 15;  // lane owns features fl*4..+3
        for (int r = 0; r < 8; ++r) {
            int t = r * 64 + wid * 4 + qid;
            int beg = (t == 0) ? 0 : cnt[t - 1];
            int end = cnt[t];
            float a0 = 0.f, a1 = 0.f, a2 = 0.f, a3 = 0.f;
            // prefetched quad (epk padded by +8: safe past end)
            unsigned pA0 = epk[beg],     pA1 = epk[beg + 1];
            unsigned pA2 = epk[beg + 2], pA3 = epk[beg + 3];
            int j = beg;
            for (; j + 4 <= end; j += 4) {
                unsigned pB0 = epk[j + 4], pB1 = epk[j + 5];
                unsigned pB2 = epk[j + 6], pB3 = epk[j + 7];
                int s0 = pA0 >> 16, s1 = pA1 >> 16, s2 = pA2 >> 16, s3 = pA3 >> 16;
                float n0 = pk_norm(pA0), n1 = pk_norm(pA1);
                float n2 = pk_norm(pA2), n3 = pk_norm(pA3);
                halfv4 x0 = *(const halfv4*)((const char*)xs_h + s0 * 128 + fl * 8);
                halfv4 x1 = *(const halfv4*)((const char*)xs_h + s1 * 128 + fl * 8);
                halfv4 x2 = *(const halfv4*)((const char*)xs_h + s2 * 128 + fl * 8);
                halfv4 x3 = *(const halfv4*)((const char*)xs_h + s3 * 128 + fl * 8);
                a0 += n0 * (float)x0[0] + n1 * (float)x1[0] + n2 * (float)x2[0] + n3 * (float)x3[0];
                a1 += n0 * (float)x0[1] + n1 * (float)x1[1] + n2 * (float)x2[1] + n3 * (float)x3[1];
                a2 += n0 * (float)x0[2] + n1 * (float)x1[2] + n2 * (float)x2[2] + n3 * (float)x3[2];
                a3 += n0 * (float)x0[3] + n1 * (float)x1[3] + n2 * (float)x2[3] + n3 * (float)x3[3];
                pA0 = pB0; pA1 = pB1; pA2 = pB2; pA3 = pB3;
            }
            for (; j < end; ++j) {                  // tail (<=3), pk already loaded
                int s = pA0 >> 16;
                float nm = pk_norm(pA0);
                halfv4 xvv = *(const halfv4*)((const char*)xs_h + s * 128 + fl * 8);
                a0 += nm * (float)xvv[0]; a1 += nm * (float)xvv[1];
                a2 += nm * (float)xvv[2]; a3 += nm * (float)xvv[3];
                pA0 = pA1; pA1 = pA2; pA2 = pA3;
            }
            halfv4 hv; hv[0]=(_Float16)a0; hv[1]=(_Float16)a1;
                       hv[2]=(_Float16)a2; hv[3]=(_Float16)a3;
            // swizzled write: 16B block (fl>>1) XOR (t&7), half (fl&1)
            int dw = t * 32 + (((fl >> 1) ^ (t & 7)) * 4) + (fl & 1) * 2;
            *(halfv4*)((char*)xhs + dw * 4) = hv;
        }
    }
    bar_lds();                                 // sync6: xhs ready

    // ---- conv (transposed tiles): D[o_loc][n_loc] = sum_k W[o][k] xh[n][k] ----
    // h element (n,o) lands at row n, 8B slot ((o>>2) ^ (n&15)), reg = o&3.
    {
        const int m = lane & 15, q = lane >> 4;
        #pragma unroll
        for (int j = 0; j < 8; ++j) {
            int idx = wid * 8 + j, tm = idx >> 2, to = idx & 3;
            int n = tm * 16 + m, o = to * 16 + m;
            halfv8 X0 = *(const halfv8*)((const char*)xhs + n * 128 + ((q       ^ (n & 7)) * 16));
            halfv8 X1 = *(const halfv8*)((const char*)xhs + n * 128 + (((4 + q) ^ (n & 7)) * 16));
            halfv8 W0 = *(const halfv8*)((const char*)wts + o * 128 + ((q       ^ (o & 7)) * 16));
            halfv8 W1 = *(const halfv8*)((const char*)wts + o * 128 + (((4 + q) ^ (o & 7)) * 16));
            f32x4 acc = {0.f, 0.f, 0.f, 0.f};
            acc = __builtin_amdgcn_mfma_f32_16x16x32_f16(W0, X0, acc, 0, 0, 0);
            acc = __builtin_amdgcn_mfma_f32_16x16x32_f16(W1, X1, acc, 0, 0, 0);
            float4 bq = *(const float4*)&wbias[to * 16 + q * 4];
            halfv4 hv;
            hv[0] = (_Float16)fmaxf(acc[0] + bq.x, 0.0f);
            hv[1] = (_Float16)fmaxf(acc[1] + bq.y, 0.0f);
            hv[2] = (_Float16)fmaxf(acc[2] + bq.z, 0.0f);
            hv[3] = (_Float16)fmaxf(acc[3] + bq.w, 0.0f);
            int sw = (to * 4 + q) ^ m;            // 8B slot within row n
            *(halfv4*)((char*)xs_h + n * 128 + sw * 8) = hv;
        }
    }
    bar_lds();                                 // sync7: h (in xs_h) ready

    // ---- fused linear tail: wave w computes logits[c=w] = h_flat . lw[c] ----
    // Lane reads its h slot-pair as ONE b128: 16B block l7 ^ ((n&15)>>1) of
    // row n holds o-groups {2*l7 + (l3&1), ^1} (verified R9/R10). Direct lw
    // loads, unroll 8 -> 8 outstanding 16B L2 reads; no register arrays.
    {
        const _Float16* lwc = lwh + (size_t)wid * (Nn * Fn);
        const int l7 = lane & 7, l3 = lane >> 3;
        const _Float16* lwp_base = lwc + l3 * 64 + l7 * 8;   // + i*512 per iter
        const int woA = (l3 & 1) * 4;
        float acc = 0.f;
        #pragma unroll 8
        for (int i = 0; i < 64; ++i) {
            halfv8 wv8 = *(const halfv8*)(lwp_base + i * 512);
            int n   = i * 8 + l3;
            int blk = l7 ^ ((n & 15) >> 1);
            halfv8 H = *(const halfv8*)((const char*)xs_h + n * 128 + blk * 16);
#if __has_builtin(__builtin_amdgcn_fdot2)
            halfv2 a0; a0[0]=H[0]; a0[1]=H[1];
            halfv2 a1; a1[0]=H[2]; a1[1]=H[3];
            halfv2 a2; a2[0]=H[4]; a2[1]=H[5];
            halfv2 a3; a3[0]=H[6]; a3[1]=H[7];
            halfv2 b0; b0[0]=wv8[woA];         b0[1]=wv8[woA + 1];
            halfv2 b1; b1[0]=wv8[woA + 2];     b1[1]=wv8[woA + 3];
            halfv2 b2; b2[0]=wv8[woA ^ 4];     b2[1]=wv8[(woA ^ 4) + 1];
            halfv2 b3; b3[0]=wv8[(woA ^ 4)+2]; b3[1]=wv8[(woA ^ 4) + 3];
            acc = __builtin_amdgcn_fdot2(a0, b0, acc, false);
            acc = __builtin_amdgcn_fdot2(a1, b1, acc, false);
            acc = __builtin_amdgcn_fdot2(a2, b2, acc, false);
            acc = __builtin_amdgcn_fdot2(a3, b3, acc, false);
#else
            acc += (float)H[0]*(float)wv8[woA]       + (float)H[1]*(float)wv8[woA + 1]
                 + (float)H[2]*(float)wv8[woA + 2]   + (float)H[3]*(float)wv8[woA + 3]
                 + (float)H[4]*(float)wv8[woA ^ 4]   + (float)H[5]*(float)wv8[(woA ^ 4) + 1]
                 + (float)H[6]*(float)wv8[(woA^4)+2] + (float)H[7]*(float)wv8[(woA ^ 4) + 3];
#endif
        }
        #pragma unroll
        for (int off = 32; off > 0; off >>= 1) acc += __shfl_xor(acc, off, 64);
        if (lane == 0) dinv[wid] = acc;            // dinv reused as logits[16]
    }
    bar_lds();                                 // sync8: logits ready

    // ---- log_softmax over 16 classes, write out[g][*] ----
    if (tid < Cn) {
        float v = dinv[tid] + lbv;
        float m = v;
        #pragma unroll
        for (int off = 8; off > 0; off >>= 1) m = fmaxf(m, __shfl_xor(m, off, 16));
        float ex = expf(v - m);
        float ssum = ex;
        #pragma unroll
        for (int off = 8; off > 0; off >>= 1) ssum += __shfl_xor(ssum, off, 16);
        out[g * Cn + tid] = v - m - logf(ssum);
    }
}

extern "C" void kernel_launch(void* const* d_in, const int* in_sizes, int n_in,
                              void* d_out, int out_size, void* d_ws, size_t ws_size,
                              hipStream_t stream) {
    const float* x  = (const float*)d_in[0];
    const int*   ei = (const int*)d_in[1];
    const float* w  = (const float*)d_in[2];
    const float* wb = (const float*)d_in[3];
    const float* lw = (const float*)d_in[4];
    const float* lb = (const float*)d_in[5];
    float* out = (float*)d_out;

    _Float16* lwh = (_Float16*)d_ws;   // 1 MB: f16 lw

    hipLaunchKernelGGL(cvt_lw, dim3(256), dim3(256), 0, stream, lw, lwh);
    hipLaunchKernelGGL(gcn_fused, dim3(Gn), dim3(1024), 0, stream,
                       x, ei, w, wb, lwh, lb, out);
}

// Round 6
// 143.065 us; speedup vs baseline: 1.0036x; 1.0036x over previous
//
#include <hip/hip_runtime.h>

// Problem constants
#define Gn 256
#define Nn 512
#define En 4096
#define Fn 64
#define Cn 16
#define ET (En + Nn)   // CSR slots including self-loops

typedef _Float16 halfv8 __attribute__((ext_vector_type(8)));
typedef _Float16 halfv4 __attribute__((ext_vector_type(4)));
typedef _Float16 halfv2 __attribute__((ext_vector_type(2)));
typedef float    f32x4  __attribute__((ext_vector_type(4)));

__device__ __forceinline__ float pk_norm(unsigned p) {
    return (float)__builtin_bit_cast(_Float16, (unsigned short)(p & 0xffffu));
}

// ---------------- K0: lw f32 -> f16 (one-time, consumed by K1 tail) ----------
__global__ __launch_bounds__(256) void cvt_lw(
    const float* __restrict__ lw,     // [16][32768] fp32
    _Float16* __restrict__ lwh)       // ws: [16][32768] f16
{
    const int i = blockIdx.x * 256 + threadIdx.x;   // 65536 threads x 8 floats
    float4 a = *((const float4*)lw + (size_t)i * 2);
    float4 b = *((const float4*)lw + (size_t)i * 2 + 1);
    halfv8 hv;
    hv[0]=(_Float16)a.x; hv[1]=(_Float16)a.y; hv[2]=(_Float16)a.z; hv[3]=(_Float16)a.w;
    hv[4]=(_Float16)b.x; hv[5]=(_Float16)b.y; hv[6]=(_Float16)b.z; hv[7]=(_Float16)b.w;
    *(halfv8*)(lwh + (size_t)i * 8) = hv;
}

// ---------------- K1: fully fused GCN per graph ----------------
// One block per graph (256 = #CUs), 1024 thr = 16 waves, ~158 KB LDS.
// R12 = R8's proven 40us schedule EXACTLY (__syncthreads everywhere; the
// R9-R11 bar_lds/sched_barrier schedule cost +30us via spills at the
// compiler's 64-VGPR budget: R11 showed 8B/thread scratch writes). Only
// graft kept: the verified tail - single ds_read_b128 slot-pair merge,
// at unroll 4 (16 in-flight lw VGPRs, R8-proven depth; fewer LDS
// instructions than R8's 2xb64 at identical register pressure).
__global__ __launch_bounds__(1024, 4) void gcn_fused(
    const float* __restrict__ x,      // [G,N,F]
    const int*   __restrict__ ei,     // [G,2,E]
    const float* __restrict__ w,      // [F_OUT,F_IN] = [64,64]
    const float* __restrict__ wbias,  // [64]
    const _Float16* __restrict__ lwh, // ws: [16][32768] f16 (from K0)
    const float* __restrict__ lbias,  // [16]
    float* __restrict__ out)          // [G,16] log-softmax
{
    __shared__ unsigned short xs_h[Nn * Fn];  // 64 KB: f16 x; reused for f16 h
    __shared__ unsigned short xhs[Nn * Fn];   // 64 KB: f16 aggregated, swizzled
    __shared__ unsigned short wts[Fn * Fn];   // 8 KB: f16 w rows, swizzled
    __shared__ unsigned int   epk[ET + 8];    // 18.5 KB: (src<<16)|f16(norm)
    __shared__ float dinv[Nn];                // degree -> rsqrt; reused: logits
    __shared__ int   cnt[Nn];                 // excl -> incl prefix
    __shared__ int   wsum[8];

    const int g    = blockIdx.x;
    const int tid  = threadIdx.x;
    const int lane = tid & 63;
    const int wid  = tid >> 6;

    const float* xg = x + (size_t)g * Nn * Fn;
    const int*   es = ei + (size_t)g * 2 * En;   // sources
    const int*   ed = es + En;                    // targets

    // ---- edges to registers (degree + CSR fill reuse them; one HBM read) ----
    const int e0s = es[tid], e1s = es[tid + 1024], e2s = es[tid + 2048], e3s = es[tid + 3072];
    const int e0t = ed[tid], e1t = ed[tid + 1024], e2t = ed[tid + 2048], e3t = ed[tid + 3072];

    if (tid < Nn) dinv[tid] = 1.0f;               // self-loop counts as 1
    __syncthreads();                              // sync0

    // ---- degree atomics from register-held targets ----
    atomicAdd(&dinv[e0t], 1.0f);
    atomicAdd(&dinv[e1t], 1.0f);
    atomicAdd(&dinv[e2t], 1.0f);
    atomicAdd(&dinv[e3t], 1.0f);

    // ---- issue x loads now; they stay in flight through scan + CSR fill ----
    float4 xv[8];
    #pragma unroll
    for (int it = 0; it < 8; ++it) xv[it] = *(const float4*)(xg + (tid + it * 1024) * 4);
    __syncthreads();                              // sync1

    // ---- per-node slot count (incl self) + dinv; exclusive prefix scan ----
    int c = 0;
    if (tid < Nn) { float d = dinv[tid]; c = (int)d; dinv[tid] = rsqrtf(d); }
    int v_ = c;
    #pragma unroll
    for (int off = 1; off < 64; off <<= 1) {
        int u = __shfl_up(v_, off, 64);
        if (lane >= off) v_ += u;
    }
    if (wid < 8 && lane == 63) wsum[wid] = v_;
    __syncthreads();                              // sync2
    if (tid == 0) { int a = 0; for (int i = 0; i < 8; ++i) { int t = wsum[i]; wsum[i] = a; a += t; } }
    __syncthreads();                              // sync3
    if (tid < Nn) cnt[tid] = v_ - c + wsum[wid];
    __syncthreads();                              // sync4

    // ---- CSR fill (edges from regs + self-loops) with packed src|norm ----
    {
        #define FILL_EDGE(ss, tt) { \
            float nrm = dinv[ss] * dinv[tt]; \
            int slot = atomicAdd(&cnt[tt], 1); \
            unsigned short nb = __builtin_bit_cast(unsigned short, (_Float16)nrm); \
            epk[slot] = ((unsigned)(ss) << 16) | nb; }
        FILL_EDGE(e0s, e0t)
        FILL_EDGE(e1s, e1t)
        FILL_EDGE(e2s, e2t)
        FILL_EDGE(e3s, e3t)
        #undef FILL_EDGE
        if (tid < Nn) {
            float dv = dinv[tid];
            float nrm = dv * dv;
            int slot = atomicAdd(&cnt[tid], 1);
            unsigned short nb = __builtin_bit_cast(unsigned short, (_Float16)nrm);
            epk[slot] = ((unsigned)tid << 16) | nb;
        }
    }

    // ---- stage w (f16, swizzled) ----
    {
        int o = tid >> 4, f0 = (tid & 15) * 4;
        float4 v = *(const float4*)(w + o * Fn + f0);
        halfv4 hv; hv[0]=(_Float16)v.x; hv[1]=(_Float16)v.y;
                   hv[2]=(_Float16)v.z; hv[3]=(_Float16)v.w;
        int blk = f0 >> 3, hf = (f0 >> 2) & 1;    // 16B-block XOR swizzle by row
        *(halfv4*)((char*)wts + o * 128 + ((blk ^ (o & 7)) * 16) + hf * 8) = hv;
    }

    // ---- stage x (f16): x loads were issued before the scan ----
    #pragma unroll
    for (int it = 0; it < 8; ++it) {
        int idx = tid + it * 1024;                // float4 index (8192 total)
        float4 v = xv[it];
        halfv4 hv; hv[0]=(_Float16)v.x; hv[1]=(_Float16)v.y;
                   hv[2]=(_Float16)v.z; hv[3]=(_Float16)v.w;
        *(halfv4*)((char*)xs_h + idx * 8) = hv;   // natural [n][f] layout
    }
    __syncthreads();                              // sync5: epk/cnt/xs_h/wts ready

    // ---- gather: quarter-wave per target, all-LDS, 4-wide pipelined ----
    {
        const int qid = lane >> 4, fl = lane & 15;  // lane owns features fl*4..+3
        for (int r = 0; r < 8; ++r) {
            int t = r * 64 + wid * 4 + qid;
            int beg = (t == 0) ? 0 : cnt[t - 1];
            int end = cnt[t];
            float a0 = 0.f, a1 = 0.f, a2 = 0.f, a3 = 0.f;
            // prefetched quad (epk padded by +8: safe past end)
            unsigned pA0 = epk[beg],     pA1 = epk[beg + 1];
            unsigned pA2 = epk[beg + 2], pA3 = epk[beg + 3];
            int j = beg;
            for (; j + 4 <= end; j += 4) {
                unsigned pB0 = epk[j + 4], pB1 = epk[j + 5];
                unsigned pB2 = epk[j + 6], pB3 = epk[j + 7];
                int s0 = pA0 >> 16, s1 = pA1 >> 16, s2 = pA2 >> 16, s3 = pA3 >> 16;
                float n0 = pk_norm(pA0), n1 = pk_norm(pA1);
                float n2 = pk_norm(pA2), n3 = pk_norm(pA3);
                halfv4 x0 = *(const halfv4*)((const char*)xs_h + s0 * 128 + fl * 8);
                halfv4 x1 = *(const halfv4*)((const char*)xs_h + s1 * 128 + fl * 8);
                halfv4 x2 = *(const halfv4*)((const char*)xs_h + s2 * 128 + fl * 8);
                halfv4 x3 = *(const halfv4*)((const char*)xs_h + s3 * 128 + fl * 8);
                a0 += n0 * (float)x0[0] + n1 * (float)x1[0] + n2 * (float)x2[0] + n3 * (float)x3[0];
                a1 += n0 * (float)x0[1] + n1 * (float)x1[1] + n2 * (float)x2[1] + n3 * (float)x3[1];
                a2 += n0 * (float)x0[2] + n1 * (float)x1[2] + n2 * (float)x2[2] + n3 * (float)x3[2];
                a3 += n0 * (float)x0[3] + n1 * (float)x1[3] + n2 * (float)x2[3] + n3 * (float)x3[3];
                pA0 = pB0; pA1 = pB1; pA2 = pB2; pA3 = pB3;
            }
            for (; j < end; ++j) {                  // tail (<=3), pk already loaded
                int s = pA0 >> 16;
                float nm = pk_norm(pA0);
                halfv4 xvv = *(const halfv4*)((const char*)xs_h + s * 128 + fl * 8);
                a0 += nm * (float)xvv[0]; a1 += nm * (float)xvv[1];
                a2 += nm * (float)xvv[2]; a3 += nm * (float)xvv[3];
                pA0 = pA1; pA1 = pA2; pA2 = pA3;
            }
            halfv4 hv; hv[0]=(_Float16)a0; hv[1]=(_Float16)a1;
                       hv[2]=(_Float16)a2; hv[3]=(_Float16)a3;
            // swizzled write: 16B block (fl>>1) XOR (t&7), half (fl&1)
            int dw = t * 32 + (((fl >> 1) ^ (t & 7)) * 4) + (fl & 1) * 2;
            *(halfv4*)((char*)xhs + dw * 4) = hv;
        }
    }
    __syncthreads();                              // sync6: xhs ready

    // ---- conv (transposed tiles): D[o_loc][n_loc] = sum_k W[o][k] xh[n][k] ----
    // h element (n,o) lands at row n, 8B slot ((o>>2) ^ (n&15)), reg = o&3.
    {
        const int m = lane & 15, q = lane >> 4;
        #pragma unroll
        for (int j = 0; j < 8; ++j) {
            int idx = wid * 8 + j, tm = idx >> 2, to = idx & 3;
            int n = tm * 16 + m, o = to * 16 + m;
            halfv8 X0 = *(const halfv8*)((const char*)xhs + n * 128 + ((q       ^ (n & 7)) * 16));
            halfv8 X1 = *(const halfv8*)((const char*)xhs + n * 128 + (((4 + q) ^ (n & 7)) * 16));
            halfv8 W0 = *(const halfv8*)((const char*)wts + o * 128 + ((q       ^ (o & 7)) * 16));
            halfv8 W1 = *(const halfv8*)((const char*)wts + o * 128 + (((4 + q) ^ (o & 7)) * 16));
            f32x4 acc = {0.f, 0.f, 0.f, 0.f};
            acc = __builtin_amdgcn_mfma_f32_16x16x32_f16(W0, X0, acc, 0, 0, 0);
            acc = __builtin_amdgcn_mfma_f32_16x16x32_f16(W1, X1, acc, 0, 0, 0);
            float4 bq = *(const float4*)&wbias[to * 16 + q * 4];
            halfv4 hv;
            hv[0] = (_Float16)fmaxf(acc[0] + bq.x, 0.0f);
            hv[1] = (_Float16)fmaxf(acc[1] + bq.y, 0.0f);
            hv[2] = (_Float16)fmaxf(acc[2] + bq.z, 0.0f);
            hv[3] = (_Float16)fmaxf(acc[3] + bq.w, 0.0f);
            int sw = (to * 4 + q) ^ m;            // 8B slot within row n
            *(halfv4*)((char*)xs_h + n * 128 + sw * 8) = hv;
        }
    }
    __syncthreads();                              // sync7: h (in xs_h) ready

    // ---- fused linear tail: wave w computes logits[c=w] = h_flat . lw[c] ----
    // Lane reads its h slot-pair as ONE b128: 16B block l7 ^ ((n&15)>>1) of
    // row n holds o-groups {2*l7 + (l3&1), ^1} (verified R9/R10/R11).
    // Direct lw loads, unroll 4 (R8-proven in-flight depth; 16 VGPRs).
    {
        const _Float16* lwc = lwh + (size_t)wid * (Nn * Fn);
        const int l7 = lane & 7, l3 = lane >> 3;
        const _Float16* lwp_base = lwc + l3 * 64 + l7 * 8;   // + i*512 per iter
        const int woA = (l3 & 1) * 4;
        float acc = 0.f;
        #pragma unroll 4
        for (int i = 0; i < 64; ++i) {
            halfv8 wv8 = *(const halfv8*)(lwp_base + i * 512);
            int n   = i * 8 + l3;
            int blk = l7 ^ ((n & 15) >> 1);
            halfv8 H = *(const halfv8*)((const char*)xs_h + n * 128 + blk * 16);
#if __has_builtin(__builtin_amdgcn_fdot2)
            halfv2 a0; a0[0]=H[0]; a0[1]=H[1];
            halfv2 a1; a1[0]=H[2]; a1[1]=H[3];
            halfv2 a2; a2[0]=H[4]; a2[1]=H[5];
            halfv2 a3; a3[0]=H[6]; a3[1]=H[7];
            halfv2 b0; b0[0]=wv8[woA];         b0[1]=wv8[woA + 1];
            halfv2 b1; b1[0]=wv8[woA + 2];     b1[1]=wv8[woA + 3];
            halfv2 b2; b2[0]=wv8[woA ^ 4];     b2[1]=wv8[(woA ^ 4) + 1];
            halfv2 b3; b3[0]=wv8[(woA ^ 4)+2]; b3[1]=wv8[(woA ^ 4) + 3];
            acc = __builtin_amdgcn_fdot2(a0, b0, acc, false);
            acc = __builtin_amdgcn_fdot2(a1, b1, acc, false);
            acc = __builtin_amdgcn_fdot2(a2, b2, acc, false);
            acc = __builtin_amdgcn_fdot2(a3, b3, acc, false);
#else
            acc += (float)H[0]*(float)wv8[woA]       + (float)H[1]*(float)wv8[woA + 1]
                 + (float)H[2]*(float)wv8[woA + 2]   + (float)H[3]*(float)wv8[woA + 3]
                 + (float)H[4]*(float)wv8[woA ^ 4]   + (float)H[5]*(float)wv8[(woA ^ 4) + 1]
                 + (float)H[6]*(float)wv8[(woA^4)+2] + (float)H[7]*(float)wv8[(woA ^ 4) + 3];
#endif
        }
        #pragma unroll
        for (int off = 32; off > 0; off >>= 1) acc += __shfl_xor(acc, off, 64);
        if (lane == 0) dinv[wid] = acc;            // dinv reused as logits[16]
    }
    __syncthreads();                              // sync8: logits ready

    // ---- log_softmax over 16 classes, write out[g][*] ----
    if (tid < Cn) {
        float v = dinv[tid] + lbias[tid];
        float m = v;
        #pragma unroll
        for (int off = 8; off > 0; off >>= 1) m = fmaxf(m, __shfl_xor(m, off, 16));
        float ex = expf(v - m);
        float ssum = ex;
        #pragma unroll
        for (int off = 8; off > 0; off >>= 1) ssum += __shfl_xor(ssum, off, 16);
        out[g * Cn + tid] = v - m - logf(ssum);
    }
}

extern "C" void kernel_launch(void* const* d_in, const int* in_sizes, int n_in,
                              void* d_out, int out_size, void* d_ws, size_t ws_size,
                              hipStream_t stream) {
    const float* x  = (const float*)d_in[0];
    const int*   ei = (const int*)d_in[1];
    const float* w  = (const float*)d_in[2];
    const float* wb = (const float*)d_in[3];
    const float* lw = (const float*)d_in[4];
    const float* lb = (const float*)d_in[5];
    float* out = (float*)d_out;

    _Float16* lwh = (_Float16*)d_ws;   // 1 MB: f16 lw

    hipLaunchKernelGGL(cvt_lw, dim3(256), dim3(256), 0, stream, lw, lwh);
    hipLaunchKernelGGL(gcn_fused, dim3(Gn), dim3(1024), 0, stream,
                       x, ei, w, wb, lwh, lb, out);
}

// Round 7
// 112.064 us; speedup vs baseline: 1.2813x; 1.2766x over previous
//
#include <hip/hip_runtime.h>

// Problem constants
#define Gn 256
#define Nn 512
#define En 4096
#define Fn 64
#define Cn 16
#define ET (En + Nn)   // CSR slots including self-loops

typedef _Float16 halfv8 __attribute__((ext_vector_type(8)));
typedef _Float16 halfv4 __attribute__((ext_vector_type(4)));
typedef _Float16 halfv2 __attribute__((ext_vector_type(2)));
typedef float    f32x4  __attribute__((ext_vector_type(4)));

__device__ __forceinline__ float pk_norm(unsigned p) {
    return (float)__builtin_bit_cast(_Float16, (unsigned short)(p & 0xffffu));
}

// ---------------- K0: lw f32 -> f16 (one-time, consumed by K1 tail) ----------
__global__ __launch_bounds__(256) void cvt_lw(
    const float* __restrict__ lw,     // [16][32768] fp32
    _Float16* __restrict__ lwh)       // ws: [16][32768] f16
{
    const int i = blockIdx.x * 256 + threadIdx.x;   // 65536 threads x 8 floats
    float4 a = *((const float4*)lw + (size_t)i * 2);
    float4 b = *((const float4*)lw + (size_t)i * 2 + 1);
    halfv8 hv;
    hv[0]=(_Float16)a.x; hv[1]=(_Float16)a.y; hv[2]=(_Float16)a.z; hv[3]=(_Float16)a.w;
    hv[4]=(_Float16)b.x; hv[5]=(_Float16)b.y; hv[6]=(_Float16)b.z; hv[7]=(_Float16)b.w;
    *(halfv8*)(lwh + (size_t)i * 8) = hv;
}

// ---------------- K1: fully fused GCN per graph ----------------
// One block per graph (256 = #CUs), 1024 thr = 16 waves, ~158 KB LDS.
// R13 = byte-exact R8 (the 113.2us champion). R9-R12 post-mortem: the sole
// shared deviation from R8 across all four regressions was the tail's
// wv8[woA] / wv8[woA^4] DYNAMIC ext_vector indexing (woA = (l3&1)*4,
// runtime) - rule #20. R8's tail uses only compile-time vector indices
// (two ds_read_b64 h-slots paired with wv8[0..7] sequentially). Restored
// verbatim; one-variable-at-a-time from here.
__global__ __launch_bounds__(1024, 4) void gcn_fused(
    const float* __restrict__ x,      // [G,N,F]
    const int*   __restrict__ ei,     // [G,2,E]
    const float* __restrict__ w,      // [F_OUT,F_IN] = [64,64]
    const float* __restrict__ wbias,  // [64]
    const _Float16* __restrict__ lwh, // ws: [16][32768] f16 (from K0)
    const float* __restrict__ lbias,  // [16]
    float* __restrict__ out)          // [G,16] log-softmax
{
    __shared__ unsigned short xs_h[Nn * Fn];  // 64 KB: f16 x; reused for f16 h
    __shared__ unsigned short xhs[Nn * Fn];   // 64 KB: f16 aggregated, swizzled
    __shared__ unsigned short wts[Fn * Fn];   // 8 KB: f16 w rows, swizzled
    __shared__ unsigned int   epk[ET + 8];    // 18.5 KB: (src<<16)|f16(norm)
    __shared__ float dinv[Nn];                // degree -> rsqrt; reused: logits
    __shared__ int   cnt[Nn];                 // excl -> incl prefix
    __shared__ int   wsum[8];

    const int g    = blockIdx.x;
    const int tid  = threadIdx.x;
    const int lane = tid & 63;
    const int wid  = tid >> 6;

    const float* xg = x + (size_t)g * Nn * Fn;
    const int*   es = ei + (size_t)g * 2 * En;   // sources
    const int*   ed = es + En;                    // targets

    // ---- edges to registers (degree + CSR fill reuse them; one HBM read) ----
    const int e0s = es[tid], e1s = es[tid + 1024], e2s = es[tid + 2048], e3s = es[tid + 3072];
    const int e0t = ed[tid], e1t = ed[tid + 1024], e2t = ed[tid + 2048], e3t = ed[tid + 3072];

    if (tid < Nn) dinv[tid] = 1.0f;               // self-loop counts as 1
    __syncthreads();

    // ---- degree atomics from register-held targets ----
    atomicAdd(&dinv[e0t], 1.0f);
    atomicAdd(&dinv[e1t], 1.0f);
    atomicAdd(&dinv[e2t], 1.0f);
    atomicAdd(&dinv[e3t], 1.0f);

    // ---- issue x loads now; they stay in flight through scan + CSR fill ----
    float4 xv[8];
    #pragma unroll
    for (int it = 0; it < 8; ++it) xv[it] = *(const float4*)(xg + (tid + it * 1024) * 4);
    __syncthreads();

    // ---- per-node slot count (incl self) + dinv; exclusive prefix scan ----
    int c = 0;
    if (tid < Nn) { float d = dinv[tid]; c = (int)d; dinv[tid] = rsqrtf(d); }
    int v_ = c;
    #pragma unroll
    for (int off = 1; off < 64; off <<= 1) {
        int u = __shfl_up(v_, off, 64);
        if (lane >= off) v_ += u;
    }
    if (wid < 8 && lane == 63) wsum[wid] = v_;
    __syncthreads();
    if (tid == 0) { int a = 0; for (int i = 0; i < 8; ++i) { int t = wsum[i]; wsum[i] = a; a += t; } }
    __syncthreads();
    if (tid < Nn) cnt[tid] = v_ - c + wsum[wid];
    __syncthreads();

    // ---- CSR fill (edges from regs + self-loops) with packed src|norm ----
    {
        #define FILL_EDGE(ss, tt) { \
            float nrm = dinv[ss] * dinv[tt]; \
            int slot = atomicAdd(&cnt[tt], 1); \
            unsigned short nb = __builtin_bit_cast(unsigned short, (_Float16)nrm); \
            epk[slot] = ((unsigned)(ss) << 16) | nb; }
        FILL_EDGE(e0s, e0t)
        FILL_EDGE(e1s, e1t)
        FILL_EDGE(e2s, e2t)
        FILL_EDGE(e3s, e3t)
        #undef FILL_EDGE
        if (tid < Nn) {
            float dv = dinv[tid];
            float nrm = dv * dv;
            int slot = atomicAdd(&cnt[tid], 1);
            unsigned short nb = __builtin_bit_cast(unsigned short, (_Float16)nrm);
            epk[slot] = ((unsigned)tid << 16) | nb;
        }
    }

    // ---- stage w (f16, swizzled) ----
    {
        int o = tid >> 4, f0 = (tid & 15) * 4;
        float4 v = *(const float4*)(w + o * Fn + f0);
        halfv4 hv; hv[0]=(_Float16)v.x; hv[1]=(_Float16)v.y;
                   hv[2]=(_Float16)v.z; hv[3]=(_Float16)v.w;
        int blk = f0 >> 3, hf = (f0 >> 2) & 1;    // 16B-block XOR swizzle by row
        *(halfv4*)((char*)wts + o * 128 + ((blk ^ (o & 7)) * 16) + hf * 8) = hv;
    }

    // ---- stage x (f16): x loads were issued before the scan ----
    #pragma unroll
    for (int it = 0; it < 8; ++it) {
        int idx = tid + it * 1024;                // float4 index (8192 total)
        float4 v = xv[it];
        halfv4 hv; hv[0]=(_Float16)v.x; hv[1]=(_Float16)v.y;
                   hv[2]=(_Float16)v.z; hv[3]=(_Float16)v.w;
        *(halfv4*)((char*)xs_h + idx * 8) = hv;   // natural [n][f] layout
    }
    __syncthreads();

    // ---- gather: quarter-wave per target, all-LDS, 4-wide pipelined ----
    {
        const int qid = lane >> 4, fl = lane & 15;  // lane owns features fl*4..+3
        for (int r = 0; r < 8; ++r) {
            int t = r * 64 + wid * 4 + qid;
            int beg = (t == 0) ? 0 : cnt[t - 1];
            int end = cnt[t];
            float a0 = 0.f, a1 = 0.f, a2 = 0.f, a3 = 0.f;
            // prefetched quad (epk padded by +8: safe past end)
            unsigned pA0 = epk[beg],     pA1 = epk[beg + 1];
            unsigned pA2 = epk[beg + 2], pA3 = epk[beg + 3];
            int j = beg;
            for (; j + 4 <= end; j += 4) {
                unsigned pB0 = epk[j + 4], pB1 = epk[j + 5];
                unsigned pB2 = epk[j + 6], pB3 = epk[j + 7];
                int s0 = pA0 >> 16, s1 = pA1 >> 16, s2 = pA2 >> 16, s3 = pA3 >> 16;
                float n0 = pk_norm(pA0), n1 = pk_norm(pA1);
                float n2 = pk_norm(pA2), n3 = pk_norm(pA3);
                halfv4 x0 = *(const halfv4*)((const char*)xs_h + s0 * 128 + fl * 8);
                halfv4 x1 = *(const halfv4*)((const char*)xs_h + s1 * 128 + fl * 8);
                halfv4 x2 = *(const halfv4*)((const char*)xs_h + s2 * 128 + fl * 8);
                halfv4 x3 = *(const halfv4*)((const char*)xs_h + s3 * 128 + fl * 8);
                a0 += n0 * (float)x0[0] + n1 * (float)x1[0] + n2 * (float)x2[0] + n3 * (float)x3[0];
                a1 += n0 * (float)x0[1] + n1 * (float)x1[1] + n2 * (float)x2[1] + n3 * (float)x3[1];
                a2 += n0 * (float)x0[2] + n1 * (float)x1[2] + n2 * (float)x2[2] + n3 * (float)x3[2];
                a3 += n0 * (float)x0[3] + n1 * (float)x1[3] + n2 * (float)x2[3] + n3 * (float)x3[3];
                pA0 = pB0; pA1 = pB1; pA2 = pB2; pA3 = pB3;
            }
            for (; j < end; ++j) {                  // tail (<=3), pk already loaded
                int s = pA0 >> 16;
                float nm = pk_norm(pA0);
                halfv4 xvv = *(const halfv4*)((const char*)xs_h + s * 128 + fl * 8);
                a0 += nm * (float)xvv[0]; a1 += nm * (float)xvv[1];
                a2 += nm * (float)xvv[2]; a3 += nm * (float)xvv[3];
                pA0 = pA1; pA1 = pA2; pA2 = pA3;
            }
            halfv4 hv; hv[0]=(_Float16)a0; hv[1]=(_Float16)a1;
                       hv[2]=(_Float16)a2; hv[3]=(_Float16)a3;
            // swizzled write: 16B block (fl>>1) XOR (t&7), half (fl&1)
            int dw = t * 32 + (((fl >> 1) ^ (t & 7)) * 4) + (fl & 1) * 2;
            *(halfv4*)((char*)xhs + dw * 4) = hv;
        }
    }
    __syncthreads();

    // ---- conv (transposed tiles): D[o_loc][n_loc] = sum_k W[o][k] xh[n][k] ----
    // h element (n,o) lands at row n, 8B slot ((o>>2) ^ (n&15)), reg = o&3.
    {
        const int m = lane & 15, q = lane >> 4;
        #pragma unroll
        for (int j = 0; j < 8; ++j) {
            int idx = wid * 8 + j, tm = idx >> 2, to = idx & 3;
            int n = tm * 16 + m, o = to * 16 + m;
            halfv8 X0 = *(const halfv8*)((const char*)xhs + n * 128 + ((q       ^ (n & 7)) * 16));
            halfv8 X1 = *(const halfv8*)((const char*)xhs + n * 128 + (((4 + q) ^ (n & 7)) * 16));
            halfv8 W0 = *(const halfv8*)((const char*)wts + o * 128 + ((q       ^ (o & 7)) * 16));
            halfv8 W1 = *(const halfv8*)((const char*)wts + o * 128 + (((4 + q) ^ (o & 7)) * 16));
            f32x4 acc = {0.f, 0.f, 0.f, 0.f};
            acc = __builtin_amdgcn_mfma_f32_16x16x32_f16(W0, X0, acc, 0, 0, 0);
            acc = __builtin_amdgcn_mfma_f32_16x16x32_f16(W1, X1, acc, 0, 0, 0);
            float4 bq = *(const float4*)&wbias[to * 16 + q * 4];
            halfv4 hv;
            hv[0] = (_Float16)fmaxf(acc[0] + bq.x, 0.0f);
            hv[1] = (_Float16)fmaxf(acc[1] + bq.y, 0.0f);
            hv[2] = (_Float16)fmaxf(acc[2] + bq.z, 0.0f);
            hv[3] = (_Float16)fmaxf(acc[3] + bq.w, 0.0f);
            int sw = (to * 4 + q) ^ m;            // 8B slot within row n
            *(halfv4*)((char*)xs_h + n * 128 + sw * 8) = hv;
        }
    }
    __syncthreads();

    // ---- fused linear tail: wave w computes logits[c=w] = h_flat . lw[c] ----
    // Lane covers k = i*512 + (lane>>3)*64 .. : row n = i*8 + (lane>>3),
    // o = (lane&7)*8..+7. All vector indices compile-time constant (the
    // R9-R12 regression was runtime wv8[woA] indexing - rule #20).
    {
        const _Float16* lwc = lwh + (size_t)wid * (Nn * Fn);
        const int l7 = lane & 7, l3 = lane >> 3;
        float acc = 0.f;
        #pragma unroll 4
        for (int i = 0; i < 64; ++i) {
            int n  = i * 8 + l3;
            int rb = n << 7;                       // row byte base
            int sA = ((l7 * 2)     ^ (n & 15));    // slot of o-group l7*2
            int sB = ((l7 * 2 + 1) ^ (n & 15));    // slot of o-group l7*2+1
            halfv4 hA = *(const halfv4*)((const char*)xs_h + rb + sA * 8);
            halfv4 hB = *(const halfv4*)((const char*)xs_h + rb + sB * 8);
            halfv8 wv8 = *(const halfv8*)(lwc + (n << 6) + l7 * 8);
#if __has_builtin(__builtin_amdgcn_fdot2)
            halfv2 a0; a0[0]=hA[0]; a0[1]=hA[1];
            halfv2 a1; a1[0]=hA[2]; a1[1]=hA[3];
            halfv2 a2; a2[0]=hB[0]; a2[1]=hB[1];
            halfv2 a3; a3[0]=hB[2]; a3[1]=hB[3];
            halfv2 b0; b0[0]=wv8[0]; b0[1]=wv8[1];
            halfv2 b1; b1[0]=wv8[2]; b1[1]=wv8[3];
            halfv2 b2; b2[0]=wv8[4]; b2[1]=wv8[5];
            halfv2 b3; b3[0]=wv8[6]; b3[1]=wv8[7];
            acc = __builtin_amdgcn_fdot2(a0, b0, acc, false);
            acc = __builtin_amdgcn_fdot2(a1, b1, acc, false);
            acc = __builtin_amdgcn_fdot2(a2, b2, acc, false);
            acc = __builtin_amdgcn_fdot2(a3, b3, acc, false);
#else
            acc += (float)hA[0]*(float)wv8[0] + (float)hA[1]*(float)wv8[1]
                 + (float)hA[2]*(float)wv8[2] + (float)hA[3]*(float)wv8[3]
                 + (float)hB[0]*(float)wv8[4] + (float)hB[1]*(float)wv8[5]
                 + (float)hB[2]*(float)wv8[6] + (float)hB[3]*(float)wv8[7];
#endif
        }
        #pragma unroll
        for (int off = 32; off > 0; off >>= 1) acc += __shfl_xor(acc, off, 64);
        if (lane == 0) dinv[wid] = acc;            // dinv reused as logits[16]
    }
    __syncthreads();

    // ---- log_softmax over 16 classes, write out[g][*] ----
    if (tid < Cn) {
        float v = dinv[tid] + lbias[tid];
        float m = v;
        #pragma unroll
        for (int off = 8; off > 0; off >>= 1) m = fmaxf(m, __shfl_xor(m, off, 16));
        float ex = expf(v - m);
        float ssum = ex;
        #pragma unroll
        for (int off = 8; off > 0; off >>= 1) ssum += __shfl_xor(ssum, off, 16);
        out[g * Cn + tid] = v - m - logf(ssum);
    }
}

extern "C" void kernel_launch(void* const* d_in, const int* in_sizes, int n_in,
                              void* d_out, int out_size, void* d_ws, size_t ws_size,
                              hipStream_t stream) {
    const float* x  = (const float*)d_in[0];
    const int*   ei = (const int*)d_in[1];
    const float* w  = (const float*)d_in[2];
    const float* wb = (const float*)d_in[3];
    const float* lw = (const float*)d_in[4];
    const float* lb = (const float*)d_in[5];
    float* out = (float*)d_out;

    _Float16* lwh = (_Float16*)d_ws;   // 1 MB: f16 lw

    hipLaunchKernelGGL(cvt_lw, dim3(256), dim3(256), 0, stream, lw, lwh);
    hipLaunchKernelGGL(gcn_fused, dim3(Gn), dim3(1024), 0, stream,
                       x, ei, w, wb, lwh, lb, out);
}

// Round 8
// 110.935 us; speedup vs baseline: 1.2943x; 1.0102x over previous
//
#include <hip/hip_runtime.h>

// Problem constants
#define Gn 256
#define Nn 512
#define En 4096
#define Fn 64
#define Cn 16
#define ET (En + Nn)   // CSR slots including self-loops

typedef _Float16 halfv8 __attribute__((ext_vector_type(8)));
typedef _Float16 halfv4 __attribute__((ext_vector_type(4)));
typedef _Float16 halfv2 __attribute__((ext_vector_type(2)));
typedef float    f32x4  __attribute__((ext_vector_type(4)));

__device__ __forceinline__ float pk_norm(unsigned p) {
    return (float)__builtin_bit_cast(_Float16, (unsigned short)(p & 0xffffu));
}

// LDS-only barrier: waits DS ops (incl. LDS atomics), leaves global loads in
// flight. Used ONLY for sync0..sync5, which guard LDS-resident data
// (dinv/cnt/epk/xs_h/wts); __syncthreads there would drain vmcnt(0) and
// serialize the 5.3us x HBM stream against the ~2.5us scan+CSR phases.
// Correctness of this barrier proven in R9/R10/R11 (all passed).
__device__ __forceinline__ void bar_lds() {
    asm volatile("s_waitcnt lgkmcnt(0)" ::: "memory");
    __builtin_amdgcn_s_barrier();
    __builtin_amdgcn_sched_barrier(0);
}

// ---------------- K0: lw f32 -> f16 (one-time, consumed by K1 tail) ----------
__global__ __launch_bounds__(256) void cvt_lw(
    const float* __restrict__ lw,     // [16][32768] fp32
    _Float16* __restrict__ lwh)       // ws: [16][32768] f16
{
    const int i = blockIdx.x * 256 + threadIdx.x;   // 65536 threads x 8 floats
    float4 a = *((const float4*)lw + (size_t)i * 2);
    float4 b = *((const float4*)lw + (size_t)i * 2 + 1);
    halfv8 hv;
    hv[0]=(_Float16)a.x; hv[1]=(_Float16)a.y; hv[2]=(_Float16)a.z; hv[3]=(_Float16)a.w;
    hv[4]=(_Float16)b.x; hv[5]=(_Float16)b.y; hv[6]=(_Float16)b.z; hv[7]=(_Float16)b.w;
    *(halfv8*)(lwh + (size_t)i * 8) = hv;
}

// ---------------- K1: fully fused GCN per graph ----------------
// One block per graph (256 = #CUs), 1024 thr = 16 waves, ~158 KB LDS.
// R14 = R13 (byte-exact R8 champion, 112.06us) + ONE change: sync0..sync5
// use bar_lds so the x stream overlaps scan+CSR. sync6..sync8 remain
// __syncthreads (no globals in flight there). Tail keeps R8's compile-time
// vector indexing (the R9-R12 regression was runtime wv8[woA] - rule #20).
__global__ __launch_bounds__(1024, 4) void gcn_fused(
    const float* __restrict__ x,      // [G,N,F]
    const int*   __restrict__ ei,     // [G,2,E]
    const float* __restrict__ w,      // [F_OUT,F_IN] = [64,64]
    const float* __restrict__ wbias,  // [64]
    const _Float16* __restrict__ lwh, // ws: [16][32768] f16 (from K0)
    const float* __restrict__ lbias,  // [16]
    float* __restrict__ out)          // [G,16] log-softmax
{
    __shared__ unsigned short xs_h[Nn * Fn];  // 64 KB: f16 x; reused for f16 h
    __shared__ unsigned short xhs[Nn * Fn];   // 64 KB: f16 aggregated, swizzled
    __shared__ unsigned short wts[Fn * Fn];   // 8 KB: f16 w rows, swizzled
    __shared__ unsigned int   epk[ET + 8];    // 18.5 KB: (src<<16)|f16(norm)
    __shared__ float dinv[Nn];                // degree -> rsqrt; reused: logits
    __shared__ int   cnt[Nn];                 // excl -> incl prefix
    __shared__ int   wsum[8];

    const int g    = blockIdx.x;
    const int tid  = threadIdx.x;
    const int lane = tid & 63;
    const int wid  = tid >> 6;

    const float* xg = x + (size_t)g * Nn * Fn;
    const int*   es = ei + (size_t)g * 2 * En;   // sources
    const int*   ed = es + En;                    // targets

    // ---- edges to registers (degree + CSR fill reuse them; one HBM read) ----
    const int e0s = es[tid], e1s = es[tid + 1024], e2s = es[tid + 2048], e3s = es[tid + 3072];
    const int e0t = ed[tid], e1t = ed[tid + 1024], e2t = ed[tid + 2048], e3t = ed[tid + 3072];

    if (tid < Nn) dinv[tid] = 1.0f;               // self-loop counts as 1
    bar_lds();                                    // sync0 (LDS-only)

    // ---- degree atomics from register-held targets ----
    atomicAdd(&dinv[e0t], 1.0f);
    atomicAdd(&dinv[e1t], 1.0f);
    atomicAdd(&dinv[e2t], 1.0f);
    atomicAdd(&dinv[e3t], 1.0f);

    // ---- issue x loads now; with bar_lds they genuinely stay in flight
    // through scan + CSR fill (no vmcnt(0) drain at the barriers) ----
    float4 xv[8];
    #pragma unroll
    for (int it = 0; it < 8; ++it) xv[it] = *(const float4*)(xg + (tid + it * 1024) * 4);
    bar_lds();                                    // sync1 (LDS-only)

    // ---- per-node slot count (incl self) + dinv; exclusive prefix scan ----
    int c = 0;
    if (tid < Nn) { float d = dinv[tid]; c = (int)d; dinv[tid] = rsqrtf(d); }
    int v_ = c;
    #pragma unroll
    for (int off = 1; off < 64; off <<= 1) {
        int u = __shfl_up(v_, off, 64);
        if (lane >= off) v_ += u;
    }
    if (wid < 8 && lane == 63) wsum[wid] = v_;
    bar_lds();                                    // sync2 (LDS-only)
    if (tid == 0) { int a = 0; for (int i = 0; i < 8; ++i) { int t = wsum[i]; wsum[i] = a; a += t; } }
    bar_lds();                                    // sync3 (LDS-only)
    if (tid < Nn) cnt[tid] = v_ - c + wsum[wid];
    bar_lds();                                    // sync4 (LDS-only)

    // ---- CSR fill (edges from regs + self-loops) with packed src|norm ----
    {
        #define FILL_EDGE(ss, tt) { \
            float nrm = dinv[ss] * dinv[tt]; \
            int slot = atomicAdd(&cnt[tt], 1); \
            unsigned short nb = __builtin_bit_cast(unsigned short, (_Float16)nrm); \
            epk[slot] = ((unsigned)(ss) << 16) | nb; }
        FILL_EDGE(e0s, e0t)
        FILL_EDGE(e1s, e1t)
        FILL_EDGE(e2s, e2t)
        FILL_EDGE(e3s, e3t)
        #undef FILL_EDGE
        if (tid < Nn) {
            float dv = dinv[tid];
            float nrm = dv * dv;
            int slot = atomicAdd(&cnt[tid], 1);
            unsigned short nb = __builtin_bit_cast(unsigned short, (_Float16)nrm);
            epk[slot] = ((unsigned)tid << 16) | nb;
        }
    }

    // ---- stage w (f16, swizzled) ----
    {
        int o = tid >> 4, f0 = (tid & 15) * 4;
        float4 v = *(const float4*)(w + o * Fn + f0);
        halfv4 hv; hv[0]=(_Float16)v.x; hv[1]=(_Float16)v.y;
                   hv[2]=(_Float16)v.z; hv[3]=(_Float16)v.w;
        int blk = f0 >> 3, hf = (f0 >> 2) & 1;    // 16B-block XOR swizzle by row
        *(halfv4*)((char*)wts + o * 128 + ((blk ^ (o & 7)) * 16) + hf * 8) = hv;
    }

    // ---- stage x (f16): waits the x stream here (compiler vmcnt on use),
    // overlapped with everything since sync1 ----
    #pragma unroll
    for (int it = 0; it < 8; ++it) {
        int idx = tid + it * 1024;                // float4 index (8192 total)
        float4 v = xv[it];
        halfv4 hv; hv[0]=(_Float16)v.x; hv[1]=(_Float16)v.y;
                   hv[2]=(_Float16)v.z; hv[3]=(_Float16)v.w;
        *(halfv4*)((char*)xs_h + idx * 8) = hv;   // natural [n][f] layout
    }
    bar_lds();                                    // sync5 (LDS-only)

    // ---- gather: quarter-wave per target, all-LDS, 4-wide pipelined ----
    {
        const int qid = lane >> 4, fl = lane & 15;  // lane owns features fl*4..+3
        for (int r = 0; r < 8; ++r) {
            int t = r * 64 + wid * 4 + qid;
            int beg = (t == 0) ? 0 : cnt[t - 1];
            int end = cnt[t];
            float a0 = 0.f, a1 = 0.f, a2 = 0.f, a3 = 0.f;
            // prefetched quad (epk padded by +8: safe past end)
            unsigned pA0 = epk[beg],     pA1 = epk[beg + 1];
            unsigned pA2 = epk[beg + 2], pA3 = epk[beg + 3];
            int j = beg;
            for (; j + 4 <= end; j += 4) {
                unsigned pB0 = epk[j + 4], pB1 = epk[j + 5];
                unsigned pB2 = epk[j + 6], pB3 = epk[j + 7];
                int s0 = pA0 >> 16, s1 = pA1 >> 16, s2 = pA2 >> 16, s3 = pA3 >> 16;
                float n0 = pk_norm(pA0), n1 = pk_norm(pA1);
                float n2 = pk_norm(pA2), n3 = pk_norm(pA3);
                halfv4 x0 = *(const halfv4*)((const char*)xs_h + s0 * 128 + fl * 8);
                halfv4 x1 = *(const halfv4*)((const char*)xs_h + s1 * 128 + fl * 8);
                halfv4 x2 = *(const halfv4*)((const char*)xs_h + s2 * 128 + fl * 8);
                halfv4 x3 = *(const halfv4*)((const char*)xs_h + s3 * 128 + fl * 8);
                a0 += n0 * (float)x0[0] + n1 * (float)x1[0] + n2 * (float)x2[0] + n3 * (float)x3[0];
                a1 += n0 * (float)x0[1] + n1 * (float)x1[1] + n2 * (float)x2[1] + n3 * (float)x3[1];
                a2 += n0 * (float)x0[2] + n1 * (float)x1[2] + n2 * (float)x2[2] + n3 * (float)x3[2];
                a3 += n0 * (float)x0[3] + n1 * (float)x1[3] + n2 * (float)x2[3] + n3 * (float)x3[3];
                pA0 = pB0; pA1 = pB1; pA2 = pB2; pA3 = pB3;
            }
            for (; j < end; ++j) {                  // tail (<=3), pk already loaded
                int s = pA0 >> 16;
                float nm = pk_norm(pA0);
                halfv4 xvv = *(const halfv4*)((const char*)xs_h + s * 128 + fl * 8);
                a0 += nm * (float)xvv[0]; a1 += nm * (float)xvv[1];
                a2 += nm * (float)xvv[2]; a3 += nm * (float)xvv[3];
                pA0 = pA1; pA1 = pA2; pA2 = pA3;
            }
            halfv4 hv; hv[0]=(_Float16)a0; hv[1]=(_Float16)a1;
                       hv[2]=(_Float16)a2; hv[3]=(_Float16)a3;
            // swizzled write: 16B block (fl>>1) XOR (t&7), half (fl&1)
            int dw = t * 32 + (((fl >> 1) ^ (t & 7)) * 4) + (fl & 1) * 2;
            *(halfv4*)((char*)xhs + dw * 4) = hv;
        }
    }
    __syncthreads();                              // sync6: xhs ready

    // ---- conv (transposed tiles): D[o_loc][n_loc] = sum_k W[o][k] xh[n][k] ----
    // h element (n,o) lands at row n, 8B slot ((o>>2) ^ (n&15)), reg = o&3.
    {
        const int m = lane & 15, q = lane >> 4;
        #pragma unroll
        for (int j = 0; j < 8; ++j) {
            int idx = wid * 8 + j, tm = idx >> 2, to = idx & 3;
            int n = tm * 16 + m, o = to * 16 + m;
            halfv8 X0 = *(const halfv8*)((const char*)xhs + n * 128 + ((q       ^ (n & 7)) * 16));
            halfv8 X1 = *(const halfv8*)((const char*)xhs + n * 128 + (((4 + q) ^ (n & 7)) * 16));
            halfv8 W0 = *(const halfv8*)((const char*)wts + o * 128 + ((q       ^ (o & 7)) * 16));
            halfv8 W1 = *(const halfv8*)((const char*)wts + o * 128 + (((4 + q) ^ (o & 7)) * 16));
            f32x4 acc = {0.f, 0.f, 0.f, 0.f};
            acc = __builtin_amdgcn_mfma_f32_16x16x32_f16(W0, X0, acc, 0, 0, 0);
            acc = __builtin_amdgcn_mfma_f32_16x16x32_f16(W1, X1, acc, 0, 0, 0);
            float4 bq = *(const float4*)&wbias[to * 16 + q * 4];
            halfv4 hv;
            hv[0] = (_Float16)fmaxf(acc[0] + bq.x, 0.0f);
            hv[1] = (_Float16)fmaxf(acc[1] + bq.y, 0.0f);
            hv[2] = (_Float16)fmaxf(acc[2] + bq.z, 0.0f);
            hv[3] = (_Float16)fmaxf(acc[3] + bq.w, 0.0f);
            int sw = (to * 4 + q) ^ m;            // 8B slot within row n
            *(halfv4*)((char*)xs_h + n * 128 + sw * 8) = hv;
        }
    }
    __syncthreads();                              // sync7: h (in xs_h) ready

    // ---- fused linear tail: wave w computes logits[c=w] = h_flat . lw[c] ----
    // Lane covers k = i*512 + (lane>>3)*64 .. : row n = i*8 + (lane>>3),
    // o = (lane&7)*8..+7. All vector indices compile-time constant (the
    // R9-R12 regression was runtime wv8[woA] indexing - rule #20).
    {
        const _Float16* lwc = lwh + (size_t)wid * (Nn * Fn);
        const int l7 = lane & 7, l3 = lane >> 3;
        float acc = 0.f;
        #pragma unroll 4
        for (int i = 0; i < 64; ++i) {
            int n  = i * 8 + l3;
            int rb = n << 7;                       // row byte base
            int sA = ((l7 * 2)     ^ (n & 15));    // slot of o-group l7*2
            int sB = ((l7 * 2 + 1) ^ (n & 15));    // slot of o-group l7*2+1
            halfv4 hA = *(const halfv4*)((const char*)xs_h + rb + sA * 8);
            halfv4 hB = *(const halfv4*)((const char*)xs_h + rb + sB * 8);
            halfv8 wv8 = *(const halfv8*)(lwc + (n << 6) + l7 * 8);
#if __has_builtin(__builtin_amdgcn_fdot2)
            halfv2 a0; a0[0]=hA[0]; a0[1]=hA[1];
            halfv2 a1; a1[0]=hA[2]; a1[1]=hA[3];
            halfv2 a2; a2[0]=hB[0]; a2[1]=hB[1];
            halfv2 a3; a3[0]=hB[2]; a3[1]=hB[3];
            halfv2 b0; b0[0]=wv8[0]; b0[1]=wv8[1];
            halfv2 b1; b1[0]=wv8[2]; b1[1]=wv8[3];
            halfv2 b2; b2[0]=wv8[4]; b2[1]=wv8[5];
            halfv2 b3; b3[0]=wv8[6]; b3[1]=wv8[7];
            acc = __builtin_amdgcn_fdot2(a0, b0, acc, false);
            acc = __builtin_amdgcn_fdot2(a1, b1, acc, false);
            acc = __builtin_amdgcn_fdot2(a2, b2, acc, false);
            acc = __builtin_amdgcn_fdot2(a3, b3, acc, false);
#else
            acc += (float)hA[0]*(float)wv8[0] + (float)hA[1]*(float)wv8[1]
                 + (float)hA[2]*(float)wv8[2] + (float)hA[3]*(float)wv8[3]
                 + (float)hB[0]*(float)wv8[4] + (float)hB[1]*(float)wv8[5]
                 + (float)hB[2]*(float)wv8[6] + (float)hB[3]*(float)wv8[7];
#endif
        }
        #pragma unroll
        for (int off = 32; off > 0; off >>= 1) acc += __shfl_xor(acc, off, 64);
        if (lane == 0) dinv[wid] = acc;            // dinv reused as logits[16]
    }
    __syncthreads();                              // sync8: logits ready

    // ---- log_softmax over 16 classes, write out[g][*] ----
    if (tid < Cn) {
        float v = dinv[tid] + lbias[tid];
        float m = v;
        #pragma unroll
        for (int off = 8; off > 0; off >>= 1) m = fmaxf(m, __shfl_xor(m, off, 16));
        float ex = expf(v - m);
        float ssum = ex;
        #pragma unroll
        for (int off = 8; off > 0; off >>= 1) ssum += __shfl_xor(ssum, off, 16);
        out[g * Cn + tid] = v - m - logf(ssum);
    }
}

extern "C" void kernel_launch(void* const* d_in, const int* in_sizes, int n_in,
                              void* d_out, int out_size, void* d_ws, size_t ws_size,
                              hipStream_t stream) {
    const float* x  = (const float*)d_in[0];
    const int*   ei = (const int*)d_in[1];
    const float* w  = (const float*)d_in[2];
    const float* wb = (const float*)d_in[3];
    const float* lw = (const float*)d_in[4];
    const float* lb = (const float*)d_in[5];
    float* out = (float*)d_out;

    _Float16* lwh = (_Float16*)d_ws;   // 1 MB: f16 lw

    hipLaunchKernelGGL(cvt_lw, dim3(256), dim3(256), 0, stream, lw, lwh);
    hipLaunchKernelGGL(gcn_fused, dim3(Gn), dim3(1024), 0, stream,
                       x, ei, w, wb, lwh, lb, out);
}

// Round 9
// 109.368 us; speedup vs baseline: 1.3129x; 1.0143x over previous
//
#include <hip/hip_runtime.h>

// Problem constants
#define Gn 256
#define Nn 512
#define En 4096
#define Fn 64
#define Cn 16
#define ET (En + Nn)   // CSR slots including self-loops

typedef _Float16 halfv8 __attribute__((ext_vector_type(8)));
typedef _Float16 halfv4 __attribute__((ext_vector_type(4)));
typedef _Float16 halfv2 __attribute__((ext_vector_type(2)));
typedef float    f32x4  __attribute__((ext_vector_type(4)));

__device__ __forceinline__ float pk_norm(unsigned p) {
    return (float)__builtin_bit_cast(_Float16, (unsigned short)(p & 0xffffu));
}

// LDS-only barrier: waits DS ops (incl. LDS atomics), leaves global loads in
// flight. Used ONLY for sync0..sync5, which guard LDS-resident data
// (dinv/cnt/epk/xs_h/wts). Perf-verified in R14 (-1.1us vs __syncthreads).
__device__ __forceinline__ void bar_lds() {
    asm volatile("s_waitcnt lgkmcnt(0)" ::: "memory");
    __builtin_amdgcn_s_barrier();
    __builtin_amdgcn_sched_barrier(0);
}

// ---------------- K0: lw f32 -> f16 (one-time, consumed by K1 tail) ----------
__global__ __launch_bounds__(256) void cvt_lw(
    const float* __restrict__ lw,     // [16][32768] fp32
    _Float16* __restrict__ lwh)       // ws: [16][32768] f16
{
    const int i = blockIdx.x * 256 + threadIdx.x;   // 65536 threads x 8 floats
    float4 a = *((const float4*)lw + (size_t)i * 2);
    float4 b = *((const float4*)lw + (size_t)i * 2 + 1);
    halfv8 hv;
    hv[0]=(_Float16)a.x; hv[1]=(_Float16)a.y; hv[2]=(_Float16)a.z; hv[3]=(_Float16)a.w;
    hv[4]=(_Float16)b.x; hv[5]=(_Float16)b.y; hv[6]=(_Float16)b.z; hv[7]=(_Float16)b.w;
    *(halfv8*)(lwh + (size_t)i * 8) = hv;
}

// ---------------- K1: fully fused GCN per graph ----------------
// One block per graph (256 = #CUs), 1024 thr = 16 waves, ~158 KB LDS.
// R15 = R14 champion (110.9us) + ONE change: gather inner loop uses
// v_dot2_f32_f16 with edge-pairing. Norms are already f16 in epk's low
// bits and x is f16 in LDS; the old path spent 16 cvt + 16 fma per 4
// edges converting both to f32. New: 8 packs + 8 dot2 (~45% VALU cut on
// the dominant phase). Products are exact either way (f16xf16 fits f32);
// only f32 summation order changes. All vector indices compile-time
// (rule #20 audited).
__global__ __launch_bounds__(1024, 4) void gcn_fused(
    const float* __restrict__ x,      // [G,N,F]
    const int*   __restrict__ ei,     // [G,2,E]
    const float* __restrict__ w,      // [F_OUT,F_IN] = [64,64]
    const float* __restrict__ wbias,  // [64]
    const _Float16* __restrict__ lwh, // ws: [16][32768] f16 (from K0)
    const float* __restrict__ lbias,  // [16]
    float* __restrict__ out)          // [G,16] log-softmax
{
    __shared__ unsigned short xs_h[Nn * Fn];  // 64 KB: f16 x; reused for f16 h
    __shared__ unsigned short xhs[Nn * Fn];   // 64 KB: f16 aggregated, swizzled
    __shared__ unsigned short wts[Fn * Fn];   // 8 KB: f16 w rows, swizzled
    __shared__ unsigned int   epk[ET + 8];    // 18.5 KB: (src<<16)|f16(norm)
    __shared__ float dinv[Nn];                // degree -> rsqrt; reused: logits
    __shared__ int   cnt[Nn];                 // excl -> incl prefix
    __shared__ int   wsum[8];

    const int g    = blockIdx.x;
    const int tid  = threadIdx.x;
    const int lane = tid & 63;
    const int wid  = tid >> 6;

    const float* xg = x + (size_t)g * Nn * Fn;
    const int*   es = ei + (size_t)g * 2 * En;   // sources
    const int*   ed = es + En;                    // targets

    // ---- edges to registers (degree + CSR fill reuse them; one HBM read) ----
    const int e0s = es[tid], e1s = es[tid + 1024], e2s = es[tid + 2048], e3s = es[tid + 3072];
    const int e0t = ed[tid], e1t = ed[tid + 1024], e2t = ed[tid + 2048], e3t = ed[tid + 3072];

    if (tid < Nn) dinv[tid] = 1.0f;               // self-loop counts as 1
    bar_lds();                                    // sync0 (LDS-only)

    // ---- degree atomics from register-held targets ----
    atomicAdd(&dinv[e0t], 1.0f);
    atomicAdd(&dinv[e1t], 1.0f);
    atomicAdd(&dinv[e2t], 1.0f);
    atomicAdd(&dinv[e3t], 1.0f);

    // ---- issue x loads now; with bar_lds they genuinely stay in flight
    // through scan + CSR fill (no vmcnt(0) drain at the barriers) ----
    float4 xv[8];
    #pragma unroll
    for (int it = 0; it < 8; ++it) xv[it] = *(const float4*)(xg + (tid + it * 1024) * 4);
    bar_lds();                                    // sync1 (LDS-only)

    // ---- per-node slot count (incl self) + dinv; exclusive prefix scan ----
    int c = 0;
    if (tid < Nn) { float d = dinv[tid]; c = (int)d; dinv[tid] = rsqrtf(d); }
    int v_ = c;
    #pragma unroll
    for (int off = 1; off < 64; off <<= 1) {
        int u = __shfl_up(v_, off, 64);
        if (lane >= off) v_ += u;
    }
    if (wid < 8 && lane == 63) wsum[wid] = v_;
    bar_lds();                                    // sync2 (LDS-only)
    if (tid == 0) { int a = 0; for (int i = 0; i < 8; ++i) { int t = wsum[i]; wsum[i] = a; a += t; } }
    bar_lds();                                    // sync3 (LDS-only)
    if (tid < Nn) cnt[tid] = v_ - c + wsum[wid];
    bar_lds();                                    // sync4 (LDS-only)

    // ---- CSR fill (edges from regs + self-loops) with packed src|norm ----
    {
        #define FILL_EDGE(ss, tt) { \
            float nrm = dinv[ss] * dinv[tt]; \
            int slot = atomicAdd(&cnt[tt], 1); \
            unsigned short nb = __builtin_bit_cast(unsigned short, (_Float16)nrm); \
            epk[slot] = ((unsigned)(ss) << 16) | nb; }
        FILL_EDGE(e0s, e0t)
        FILL_EDGE(e1s, e1t)
        FILL_EDGE(e2s, e2t)
        FILL_EDGE(e3s, e3t)
        #undef FILL_EDGE
        if (tid < Nn) {
            float dv = dinv[tid];
            float nrm = dv * dv;
            int slot = atomicAdd(&cnt[tid], 1);
            unsigned short nb = __builtin_bit_cast(unsigned short, (_Float16)nrm);
            epk[slot] = ((unsigned)tid << 16) | nb;
        }
    }

    // ---- stage w (f16, swizzled) ----
    {
        int o = tid >> 4, f0 = (tid & 15) * 4;
        float4 v = *(const float4*)(w + o * Fn + f0);
        halfv4 hv; hv[0]=(_Float16)v.x; hv[1]=(_Float16)v.y;
                   hv[2]=(_Float16)v.z; hv[3]=(_Float16)v.w;
        int blk = f0 >> 3, hf = (f0 >> 2) & 1;    // 16B-block XOR swizzle by row
        *(halfv4*)((char*)wts + o * 128 + ((blk ^ (o & 7)) * 16) + hf * 8) = hv;
    }

    // ---- stage x (f16): waits the x stream here (compiler vmcnt on use),
    // overlapped with everything since sync1 ----
    #pragma unroll
    for (int it = 0; it < 8; ++it) {
        int idx = tid + it * 1024;                // float4 index (8192 total)
        float4 v = xv[it];
        halfv4 hv; hv[0]=(_Float16)v.x; hv[1]=(_Float16)v.y;
                   hv[2]=(_Float16)v.z; hv[3]=(_Float16)v.w;
        *(halfv4*)((char*)xs_h + idx * 8) = hv;   // natural [n][f] layout
    }
    bar_lds();                                    // sync5 (LDS-only)

    // ---- gather: quarter-wave per target, all-LDS, 4-wide pipelined,
    // edge-paired v_dot2_f32_f16 (norms stay f16, x stays f16) ----
    {
        const int qid = lane >> 4, fl = lane & 15;  // lane owns features fl*4..+3
        for (int r = 0; r < 8; ++r) {
            int t = r * 64 + wid * 4 + qid;
            int beg = (t == 0) ? 0 : cnt[t - 1];
            int end = cnt[t];
            float a0 = 0.f, a1 = 0.f, a2 = 0.f, a3 = 0.f;
            // prefetched quad (epk padded by +8: safe past end)
            unsigned pA0 = epk[beg],     pA1 = epk[beg + 1];
            unsigned pA2 = epk[beg + 2], pA3 = epk[beg + 3];
            int j = beg;
            for (; j + 4 <= end; j += 4) {
                unsigned pB0 = epk[j + 4], pB1 = epk[j + 5];
                unsigned pB2 = epk[j + 6], pB3 = epk[j + 7];
                int s0 = pA0 >> 16, s1 = pA1 >> 16, s2 = pA2 >> 16, s3 = pA3 >> 16;
                halfv4 x0 = *(const halfv4*)((const char*)xs_h + s0 * 128 + fl * 8);
                halfv4 x1 = *(const halfv4*)((const char*)xs_h + s1 * 128 + fl * 8);
                halfv4 x2 = *(const halfv4*)((const char*)xs_h + s2 * 128 + fl * 8);
                halfv4 x3 = *(const halfv4*)((const char*)xs_h + s3 * 128 + fl * 8);
#if __has_builtin(__builtin_amdgcn_fdot2)
                halfv2 n01 = __builtin_bit_cast(halfv2, (pA0 & 0xffffu) | (pA1 << 16));
                halfv2 n23 = __builtin_bit_cast(halfv2, (pA2 & 0xffffu) | (pA3 << 16));
                halfv2 p;                          // all indices compile-time
                p[0] = x0[0]; p[1] = x1[0]; a0 = __builtin_amdgcn_fdot2(p, n01, a0, false);
                p[0] = x2[0]; p[1] = x3[0]; a0 = __builtin_amdgcn_fdot2(p, n23, a0, false);
                p[0] = x0[1]; p[1] = x1[1]; a1 = __builtin_amdgcn_fdot2(p, n01, a1, false);
                p[0] = x2[1]; p[1] = x3[1]; a1 = __builtin_amdgcn_fdot2(p, n23, a1, false);
                p[0] = x0[2]; p[1] = x1[2]; a2 = __builtin_amdgcn_fdot2(p, n01, a2, false);
                p[0] = x2[2]; p[1] = x3[2]; a2 = __builtin_amdgcn_fdot2(p, n23, a2, false);
                p[0] = x0[3]; p[1] = x1[3]; a3 = __builtin_amdgcn_fdot2(p, n01, a3, false);
                p[0] = x2[3]; p[1] = x3[3]; a3 = __builtin_amdgcn_fdot2(p, n23, a3, false);
#else
                float n0 = pk_norm(pA0), n1 = pk_norm(pA1);
                float n2 = pk_norm(pA2), n3 = pk_norm(pA3);
                a0 += n0 * (float)x0[0] + n1 * (float)x1[0] + n2 * (float)x2[0] + n3 * (float)x3[0];
                a1 += n0 * (float)x0[1] + n1 * (float)x1[1] + n2 * (float)x2[1] + n3 * (float)x3[1];
                a2 += n0 * (float)x0[2] + n1 * (float)x1[2] + n2 * (float)x2[2] + n3 * (float)x3[2];
                a3 += n0 * (float)x0[3] + n1 * (float)x1[3] + n2 * (float)x2[3] + n3 * (float)x3[3];
#endif
                pA0 = pB0; pA1 = pB1; pA2 = pB2; pA3 = pB3;
            }
            for (; j < end; ++j) {                  // tail (<=3), pk already loaded
                int s = pA0 >> 16;
                float nm = pk_norm(pA0);
                halfv4 xvv = *(const halfv4*)((const char*)xs_h + s * 128 + fl * 8);
                a0 += nm * (float)xvv[0]; a1 += nm * (float)xvv[1];
                a2 += nm * (float)xvv[2]; a3 += nm * (float)xvv[3];
                pA0 = pA1; pA1 = pA2; pA2 = pA3;
            }
            halfv4 hv; hv[0]=(_Float16)a0; hv[1]=(_Float16)a1;
                       hv[2]=(_Float16)a2; hv[3]=(_Float16)a3;
            // swizzled write: 16B block (fl>>1) XOR (t&7), half (fl&1)
            int dw = t * 32 + (((fl >> 1) ^ (t & 7)) * 4) + (fl & 1) * 2;
            *(halfv4*)((char*)xhs + dw * 4) = hv;
        }
    }
    __syncthreads();                              // sync6: xhs ready

    // ---- conv (transposed tiles): D[o_loc][n_loc] = sum_k W[o][k] xh[n][k] ----
    // h element (n,o) lands at row n, 8B slot ((o>>2) ^ (n&15)), reg = o&3.
    {
        const int m = lane & 15, q = lane >> 4;
        #pragma unroll
        for (int j = 0; j < 8; ++j) {
            int idx = wid * 8 + j, tm = idx >> 2, to = idx & 3;
            int n = tm * 16 + m, o = to * 16 + m;
            halfv8 X0 = *(const halfv8*)((const char*)xhs + n * 128 + ((q       ^ (n & 7)) * 16));
            halfv8 X1 = *(const halfv8*)((const char*)xhs + n * 128 + (((4 + q) ^ (n & 7)) * 16));
            halfv8 W0 = *(const halfv8*)((const char*)wts + o * 128 + ((q       ^ (o & 7)) * 16));
            halfv8 W1 = *(const halfv8*)((const char*)wts + o * 128 + (((4 + q) ^ (o & 7)) * 16));
            f32x4 acc = {0.f, 0.f, 0.f, 0.f};
            acc = __builtin_amdgcn_mfma_f32_16x16x32_f16(W0, X0, acc, 0, 0, 0);
            acc = __builtin_amdgcn_mfma_f32_16x16x32_f16(W1, X1, acc, 0, 0, 0);
            float4 bq = *(const float4*)&wbias[to * 16 + q * 4];
            halfv4 hv;
            hv[0] = (_Float16)fmaxf(acc[0] + bq.x, 0.0f);
            hv[1] = (_Float16)fmaxf(acc[1] + bq.y, 0.0f);
            hv[2] = (_Float16)fmaxf(acc[2] + bq.z, 0.0f);
            hv[3] = (_Float16)fmaxf(acc[3] + bq.w, 0.0f);
            int sw = (to * 4 + q) ^ m;            // 8B slot within row n
            *(halfv4*)((char*)xs_h + n * 128 + sw * 8) = hv;
        }
    }
    __syncthreads();                              // sync7: h (in xs_h) ready

    // ---- fused linear tail: wave w computes logits[c=w] = h_flat . lw[c] ----
    // Lane covers k = i*512 + (lane>>3)*64 .. : row n = i*8 + (lane>>3),
    // o = (lane&7)*8..+7. All vector indices compile-time constant (the
    // R9-R12 regression was runtime wv8[woA] indexing - rule #20).
    {
        const _Float16* lwc = lwh + (size_t)wid * (Nn * Fn);
        const int l7 = lane & 7, l3 = lane >> 3;
        float acc = 0.f;
        #pragma unroll 4
        for (int i = 0; i < 64; ++i) {
            int n  = i * 8 + l3;
            int rb = n << 7;                       // row byte base
            int sA = ((l7 * 2)     ^ (n & 15));    // slot of o-group l7*2
            int sB = ((l7 * 2 + 1) ^ (n & 15));    // slot of o-group l7*2+1
            halfv4 hA = *(const halfv4*)((const char*)xs_h + rb + sA * 8);
            halfv4 hB = *(const halfv4*)((const char*)xs_h + rb + sB * 8);
            halfv8 wv8 = *(const halfv8*)(lwc + (n << 6) + l7 * 8);
#if __has_builtin(__builtin_amdgcn_fdot2)
            halfv2 a0; a0[0]=hA[0]; a0[1]=hA[1];
            halfv2 a1; a1[0]=hA[2]; a1[1]=hA[3];
            halfv2 a2; a2[0]=hB[0]; a2[1]=hB[1];
            halfv2 a3; a3[0]=hB[2]; a3[1]=hB[3];
            halfv2 b0; b0[0]=wv8[0]; b0[1]=wv8[1];
            halfv2 b1; b1[0]=wv8[2]; b1[1]=wv8[3];
            halfv2 b2; b2[0]=wv8[4]; b2[1]=wv8[5];
            halfv2 b3; b3[0]=wv8[6]; b3[1]=wv8[7];
            acc = __builtin_amdgcn_fdot2(a0, b0, acc, false);
            acc = __builtin_amdgcn_fdot2(a1, b1, acc, false);
            acc = __builtin_amdgcn_fdot2(a2, b2, acc, false);
            acc = __builtin_amdgcn_fdot2(a3, b3, acc, false);
#else
            acc += (float)hA[0]*(float)wv8[0] + (float)hA[1]*(float)wv8[1]
                 + (float)hA[2]*(float)wv8[2] + (float)hA[3]*(float)wv8[3]
                 + (float)hB[0]*(float)wv8[4] + (float)hB[1]*(float)wv8[5]
                 + (float)hB[2]*(float)wv8[6] + (float)hB[3]*(float)wv8[7];
#endif
        }
        #pragma unroll
        for (int off = 32; off > 0; off >>= 1) acc += __shfl_xor(acc, off, 64);
        if (lane == 0) dinv[wid] = acc;            // dinv reused as logits[16]
    }
    __syncthreads();                              // sync8: logits ready

    // ---- log_softmax over 16 classes, write out[g][*] ----
    if (tid < Cn) {
        float v = dinv[tid] + lbias[tid];
        float m = v;
        #pragma unroll
        for (int off = 8; off > 0; off >>= 1) m = fmaxf(m, __shfl_xor(m, off, 16));
        float ex = expf(v - m);
        float ssum = ex;
        #pragma unroll
        for (int off = 8; off > 0; off >>= 1) ssum += __shfl_xor(ssum, off, 16);
        out[g * Cn + tid] = v - m - logf(ssum);
    }
}

extern "C" void kernel_launch(void* const* d_in, const int* in_sizes, int n_in,
                              void* d_out, int out_size, void* d_ws, size_t ws_size,
                              hipStream_t stream) {
    const float* x  = (const float*)d_in[0];
    const int*   ei = (const int*)d_in[1];
    const float* w  = (const float*)d_in[2];
    const float* wb = (const float*)d_in[3];
    const float* lw = (const float*)d_in[4];
    const float* lb = (const float*)d_in[5];
    float* out = (float*)d_out;

    _Float16* lwh = (_Float16*)d_ws;   // 1 MB: f16 lw

    hipLaunchKernelGGL(cvt_lw, dim3(256), dim3(256), 0, stream, lw, lwh);
    hipLaunchKernelGGL(gcn_fused, dim3(Gn), dim3(1024), 0, stream,
                       x, ei, w, wb, lwh, lb, out);
}